// Round 6
// baseline (479.018 us; speedup 1.0000x reference)
//
#include <hip/hip_runtime.h>
#include <stdint.h>

// ---------------------------------------------------------------------------
// TransformerBlock: RoPE -> QKV -> sliding-window attention (WIN=256) ->
// out_proj -> +res LN1 -> FFN(GELU tanh-form) -> +res LN2.
// B=8, S=1024, E=1024, H=16, HD=64. All GEMMs via bf16 MFMA 16x16x32.
// GEMM: 128x128 tile, BK=64, XOR-swizzled LDS, XCD-clustered tile decode.
// ---------------------------------------------------------------------------

#define B_ 8
#define S_ 1024
#define E_ 1024
#define H_ 16
#define HD_ 64
#define WIN_ 256
#define QKV_ 3072   // merged QKV row stride

typedef __attribute__((ext_vector_type(8))) short short8;
typedef __attribute__((ext_vector_type(4))) float f32x4;
typedef __attribute__((ext_vector_type(4))) unsigned short us4;
typedef __attribute__((ext_vector_type(4))) unsigned int u32x4;
typedef unsigned short ushort_t;

__device__ __forceinline__ ushort_t f2b(float f) {
  unsigned int u = __builtin_bit_cast(unsigned int, f);
  u = (u + 0x7fffu + ((u >> 16) & 1u)) >> 16;
  return (ushort_t)u;
}

__device__ __forceinline__ float b2f(ushort_t u) {
  return __builtin_bit_cast(float, ((unsigned int)u) << 16);
}

__device__ __forceinline__ float fast_exp2(float x) {
#if __has_builtin(__builtin_amdgcn_exp2f)
  return __builtin_amdgcn_exp2f(x);
#else
  return exp2f(x);
#endif
}

__device__ __forceinline__ float fast_rcp(float x) {
#if __has_builtin(__builtin_amdgcn_rcpf)
  return __builtin_amdgcn_rcpf(x);
#else
  return 1.f / x;
#endif
}

__device__ __forceinline__ void gld_lds16(const void* g, void* l) {
  __builtin_amdgcn_global_load_lds((const __attribute__((address_space(1))) void*)g,
                                   (__attribute__((address_space(3))) void*)l, 16, 0, 0);
}

// ---------------------------------------------------------------------------
// All four weight casts in one launch.
// ---------------------------------------------------------------------------
__global__ __launch_bounds__(256) void cast4_kernel(const float* __restrict__ i0,
                                                    const float* __restrict__ i1,
                                                    const float* __restrict__ i2,
                                                    const float* __restrict__ i3,
                                                    ushort_t* __restrict__ o0,
                                                    ushort_t* __restrict__ o1,
                                                    ushort_t* __restrict__ o2,
                                                    ushort_t* __restrict__ o3) {
  int i = blockIdx.x * 256 + threadIdx.x;
  const float* in;
  ushort_t* out;
  int j;
  if (i < 786432)       { in = i0; out = o0; j = i; }
  else if (i < 1048576) { in = i1; out = o1; j = i - 786432; }
  else if (i < 2097152) { in = i2; out = o2; j = i - 1048576; }
  else                  { in = i3; out = o3; j = i - 2097152; }
  float4 v = ((const float4*)in)[j];
  us4 o;
  o.x = f2b(v.x); o.y = f2b(v.y); o.z = f2b(v.z); o.w = f2b(v.w);
  ((us4*)out)[j] = o;
}

// ---------------------------------------------------------------------------
// RoPE on raw input; emits roped (bf16) and plain x (bf16) for the V proj.
// ---------------------------------------------------------------------------
__global__ __launch_bounds__(256) void rope_kernel(const float* __restrict__ x,
                                                   ushort_t* __restrict__ roped,
                                                   ushort_t* __restrict__ xbf) {
  int idx = blockIdx.x * 256 + threadIdx.x;   // B*S*H*32 = 4,194,304
  int d = idx & 31;
  int h = (idx >> 5) & 15;
  int s = (idx >> 9) & 1023;
  int b = idx >> 19;
  size_t base = ((size_t)(b * S_ + s)) * E_ + h * HD_ + d;
  float x0 = x[base], x1 = x[base + 32];
  float freq = exp2f(-(float)d * 0.41524101186092029f);
  float th = (float)s * freq;
  float sn, cs;
  sincosf(th, &sn, &cs);
  roped[base]      = f2b(x0 * cs - x1 * sn);
  roped[base + 32] = f2b(x1 * cs + x0 * sn);
  xbf[base]      = f2b(x0);
  xbf[base + 32] = f2b(x1);
}

// ---------------------------------------------------------------------------
// GEMM: C[M][N] = A[M][K] @ B[N][K]^T + bias, bf16 in, fp32 acc. 128x128 tile,
// BK=64, 4 waves. XOR-swizzled LDS (conflict-free). 1-D grid with
// XCD-clustered decode: xcd = bid&7 owns bm-tiles 8*xcd..8*xcd+7 and sweeps
// bn -> each XCD's A working set (2 MB) stays L2-resident, so the per-iter
// vmcnt(0) barrier drain waits on L2 (~200cy) instead of HBM (~900cy).
// MODE: 0 = bf16 out, 1 = bf16 out + GELU(tanh-form).
// A2/nsplit: column-dependent A select (merged QKV: cols >= nsplit use A2).
// M is fixed 8192 (64 bm-tiles).
// ---------------------------------------------------------------------------
template <int MODE>
__global__ __launch_bounds__(256) void gemm_bt(const ushort_t* __restrict__ A,
                                               const ushort_t* __restrict__ A2,
                                               int nsplit,
                                               const ushort_t* __restrict__ Bm,
                                               const float* __restrict__ bias,
                                               ushort_t* __restrict__ C,
                                               int N, int K) {
  __shared__ ushort_t sA[128 * 64];   // 16 KB
  __shared__ ushort_t sB[128 * 64];   // 16 KB
  const int tid = threadIdx.x;
  const int lane = tid & 63;
  const int wave = tid >> 6;
  const int quad = lane >> 4;
  const int lq = lane & 15;
  const int wm = (wave & 1) * 64;
  const int wn = (wave >> 1) * 64;
  // XCD-clustered decode (gx = 64 fixed)
  const int bid = blockIdx.x;
  const int bx = ((bid & 7) << 3) | ((bid >> 3) & 7);
  const int by = bid >> 6;
  const size_t bm = (size_t)bx * 128;
  const size_t bn = (size_t)by * 128;
  const ushort_t* Asel = (bn >= (size_t)nsplit) ? A2 : A;

  f32x4 acc[4][4] = {};

  const int srow = lane >> 3;                       // row within 8-row group
  const int skc = ((lane & 7) ^ (lane >> 3)) * 8;   // logical k-chunk offset

  for (int k0 = 0; k0 < K; k0 += 64) {
#pragma unroll
    for (int i = 0; i < 4; i++) {
      const int r0 = wave * 32 + i * 8;
      gld_lds16(Asel + (bm + r0 + srow) * K + k0 + skc, &sA[r0 * 64]);
      gld_lds16(Bm + (bn + r0 + srow) * K + k0 + skc, &sB[r0 * 64]);
    }
    __syncthreads();

#pragma unroll
    for (int kk = 0; kk < 2; kk++) {
      const int csw = (((kk * 4) + quad) ^ (lq & 7)) * 8;   // phys chunk offset
      short8 av[4], bv[4];
#pragma unroll
      for (int mt = 0; mt < 4; mt++)
        av[mt] = *(const short8*)&sA[(wm + mt * 16 + lq) * 64 + csw];
#pragma unroll
      for (int nt = 0; nt < 4; nt++)
        bv[nt] = *(const short8*)&sB[(wn + nt * 16 + lq) * 64 + csw];
#pragma unroll
      for (int mt = 0; mt < 4; mt++)
#pragma unroll
        for (int nt = 0; nt < 4; nt++)
          acc[mt][nt] = __builtin_amdgcn_mfma_f32_16x16x32_bf16(av[mt], bv[nt], acc[mt][nt], 0, 0, 0);
    }
    __syncthreads();
  }

#pragma unroll
  for (int mt = 0; mt < 4; mt++) {
#pragma unroll
    for (int nt = 0; nt < 4; nt++) {
      size_t row = bm + wm + mt * 16 + quad * 4;
      size_t col = bn + wn + nt * 16 + lq;
      float bc = bias[col];
#pragma unroll
      for (int r = 0; r < 4; r++) {
        float v = acc[mt][nt][r] + bc;
        if (MODE == 1) {
          float y = 0.7978845608028654f * (v + 0.044715f * v * v * v);
          float t = fast_exp2(y * 2.8853900817779268f);
          v = v * (t * fast_rcp(1.f + t));
        }
        C[(row + r) * N + col] = f2b(v);
      }
    }
  }
}

// ---------------------------------------------------------------------------
// V transpose: qkv[b*S+s][2048 + h*64 + d] -> vt[((b*16+h)*64+d)*S + s]
// ---------------------------------------------------------------------------
__global__ __launch_bounds__(256) void vtrans_kernel(const ushort_t* __restrict__ qkv,
                                                     ushort_t* __restrict__ vt) {
  __shared__ ushort_t tb[64 * 65];
  int bh = blockIdx.x >> 4;    // 0..127
  int st = blockIdx.x & 15;
  int b = bh >> 4, h = bh & 15;
  int s0 = st * 64;
  int tid = threadIdx.x;
  int c = tid & 63, rbase = tid >> 6;
#pragma unroll
  for (int rep = 0; rep < 16; rep++) {
    int i = rep * 4 + rbase;  // s-local
    tb[c * 65 + i] = qkv[(size_t)(b * S_ + s0 + i) * QKV_ + 2048 + h * HD_ + c];
  }
  __syncthreads();
#pragma unroll
  for (int rep = 0; rep < 16; rep++) {
    int d = rep * 4 + rbase;  // head-dim
    vt[(size_t)((b * H_ + h) * HD_ + d) * S_ + s0 + c] = tb[d * 65 + c];
  }
}

// ---------------------------------------------------------------------------
// Sliding-window flash attention v5: S^T layout, zero cross-lane in loop.
// QK computed with SWAPPED operands: mfma(K_frag, Q_frag) -> D col=q(lq),
// row=key(quad*4+r). Then lane (lq,quad) locally owns P for q=lq at keys
// {4q..4q+3 (t0), 16+4q..16+4q+3 (t1)} — exactly the 16x16x32 A-operand
// slots k=quad*8+j with slot order [t0 keys | t1 keys]. V fragments read in
// the same slot order (two ds_read_b64 per nt). No sP LDS round-trip, no
// in-loop barrier for P, denominator is a per-lane scalar reduced at the end.
// Block-cooperative double-buffered K/V staging via global_load_lds.
// ---------------------------------------------------------------------------
#define SC_ 0.18033688011112042f  // 0.125 * log2(e)

__global__ __launch_bounds__(256) void attn_kernel(const ushort_t* __restrict__ qkv,
                                                   const ushort_t* __restrict__ vt,
                                                   ushort_t* __restrict__ ctx) {
  __shared__ ushort_t sK[2][32 * 64];   // [key][dim], rows 128B, XOR(row&7)
  __shared__ ushort_t sV[2][64 * 32];   // [dim][key], rows 64B, XOR((row>>1)&3)
  const int tid = threadIdx.x;
  const int lane = tid & 63, wave = tid >> 6;
  const int quad = lane >> 4, lq = lane & 15;
  int gid = ((blockIdx.x & 7) << 8) | (blockIdx.x >> 3);
  int qs = gid & 15;          // 64-query super-tile
  int h = (gid >> 4) & 15;
  int b = gid >> 8;
  int qs64 = qs * 64;
  int q0 = qs64 + wave * 16;

  // Q fragments (used as B-operand): rows q0+lq, dims quad*8+j (+32)
  const size_t qoff = (size_t)(b * S_ + q0 + lq) * QKV_ + h * HD_;
  short8 a0 = *(const short8*)&qkv[qoff + quad * 8];
  short8 a1 = *(const short8*)&qkv[qoff + 32 + quad * 8];

  f32x4 o[4] = {};
  float rs = 0.f;   // per-lane denominator partial (q = lq)

  int start = qs64 - WIN_; if (start < 0) start = 0;
  int end = qs64 + 64 + WIN_; if (end > S_) end = S_;
  const int wlo = q0 - WIN_;
  const int whi = q0 + 16 + WIN_;

  const ushort_t* kg = qkv + (size_t)(b * S_) * QKV_ + 1024 + h * HD_;
  const ushort_t* vg = vt + (size_t)((b * H_ + h) * HD_) * S_;

  const int krow = lane >> 3;
  const int kchg = ((lane & 7) ^ krow) << 3;
  const int vrow = lane >> 2;
  const int vchg = ((lane & 3) ^ ((lane >> 3) & 3)) << 3;

  gld_lds16(kg + (size_t)(start + wave * 8 + krow) * QKV_ + kchg, &sK[0][wave * 512]);
  gld_lds16(vg + (size_t)(wave * 16 + vrow) * S_ + start + vchg, &sV[0][wave * 512]);

  const int nch = (end - start) >> 5;
  int buf = 0;
  const int r3 = (lq >> 1) & 3;          // sV read swizzle
  const int qi = q0 + lq;
  for (int c = 0; c < nch; c++) {
    __syncthreads();
    int kb = start + c * 32;
    if (c + 1 < nch) {
      int nkb = kb + 32;
      gld_lds16(kg + (size_t)(nkb + wave * 8 + krow) * QKV_ + kchg, &sK[buf ^ 1][wave * 512]);
      gld_lds16(vg + (size_t)(wave * 16 + vrow) * S_ + nkb + vchg, &sV[buf ^ 1][wave * 512]);
    }
    if (kb < whi && kb + 32 > wlo) {
      // ---- S^T tiles: rows=keys, cols=q ----
      f32x4 s[2];
#pragma unroll
      for (int t = 0; t < 2; t++) {
        const ushort_t* kr = &sK[buf][(t * 16 + lq) * 64];
        short8 b0 = *(const short8*)&kr[((quad ^ (lq & 7)) << 3)];
        short8 b1 = *(const short8*)&kr[(((4 + quad) ^ (lq & 7)) << 3)];
        f32x4 z = {};
        z = __builtin_amdgcn_mfma_f32_16x16x32_bf16(b0, a0, z, 0, 0, 0);  // swapped
        z = __builtin_amdgcn_mfma_f32_16x16x32_bf16(b1, a1, z, 0, 0, 0);
        s[t] = z;
      }
      // ---- p = exp2(s*SC); mask only near window edges ----
      float p[2][4];
      const bool full = (kb >= q0 - 241) && (kb <= q0 + 225);
      if (full) {
#pragma unroll
        for (int t = 0; t < 2; t++)
#pragma unroll
          for (int r = 0; r < 4; r++) p[t][r] = fast_exp2(s[t][r] * SC_);
      } else {
#pragma unroll
        for (int t = 0; t < 2; t++) {
          int kbase_t = kb + t * 16 + quad * 4;
#pragma unroll
          for (int r = 0; r < 4; r++) {
            int dd = qi - (kbase_t + r);
            bool allowed = (dd <= WIN_) && (dd >= -WIN_);
            p[t][r] = allowed ? fast_exp2(s[t][r] * SC_) : 0.f;
          }
        }
      }
      rs += p[0][0] + p[0][1] + p[0][2] + p[0][3] +
            p[1][0] + p[1][1] + p[1][2] + p[1][3];

      // ---- pack P into A-operand slots [t0 keys | t1 keys], lane-local ----
      u32x4 pk;
      {
        unsigned int u00 = __builtin_bit_cast(unsigned int, p[0][0]);
        unsigned int u01 = __builtin_bit_cast(unsigned int, p[0][1]);
        unsigned int u02 = __builtin_bit_cast(unsigned int, p[0][2]);
        unsigned int u03 = __builtin_bit_cast(unsigned int, p[0][3]);
        unsigned int u10 = __builtin_bit_cast(unsigned int, p[1][0]);
        unsigned int u11 = __builtin_bit_cast(unsigned int, p[1][1]);
        unsigned int u12 = __builtin_bit_cast(unsigned int, p[1][2]);
        unsigned int u13 = __builtin_bit_cast(unsigned int, p[1][3]);
        pk.x = (u01 & 0xFFFF0000u) | (u00 >> 16);
        pk.y = (u03 & 0xFFFF0000u) | (u02 >> 16);
        pk.z = (u11 & 0xFFFF0000u) | (u10 >> 16);
        pk.w = (u13 & 0xFFFF0000u) | (u12 >> 16);
      }
      short8 ap = __builtin_bit_cast(short8, pk);

      // ---- PV: V fragment in matching slot order (2x ds_read_b64 / nt) ----
#pragma unroll
      for (int nt = 0; nt < 4; nt++) {
        const uint2* vrow2 = (const uint2*)&sV[buf][(nt * 16 + lq) * 32];
        uint2 lo = vrow2[(((quad >> 1)) ^ r3) * 2 + (quad & 1)];
        uint2 hi = vrow2[(((quad >> 1) + 2) ^ r3) * 2 + (quad & 1)];
        u32x4 vv; vv.x = lo.x; vv.y = lo.y; vv.z = hi.x; vv.w = hi.y;
        short8 bvf = __builtin_bit_cast(short8, vv);
        o[nt] = __builtin_amdgcn_mfma_f32_16x16x32_bf16(ap, bvf, o[nt], 0, 0, 0);
      }
    }
    buf ^= 1;
  }

  // ---- denominator: reduce across quads (each lane: q = lq) ----
  rs += __shfl_xor(rs, 16);
  rs += __shfl_xor(rs, 32);
  // redistribute: output row q = quad*4+r needs denom from lane (quad*4+r)
  float inv[4];
#pragma unroll
  for (int r = 0; r < 4; r++)
    inv[r] = fast_rcp(__shfl(rs, quad * 4 + r));

  // ---- normalize + store ctx ----
#pragma unroll
  for (int nt = 0; nt < 4; nt++)
#pragma unroll
    for (int r = 0; r < 4; r++) {
      int row = q0 + quad * 4 + r;
      int col = h * HD_ + nt * 16 + lq;
      ctx[(size_t)(b * S_ + row) * E_ + col] = f2b(o[nt][r] * inv[r]);
    }
}

// ---------------------------------------------------------------------------
// y = A + Bv (residual, Bv bf16); out = LN(y)*g + b. outf fp32; outb bf16 opt.
// ---------------------------------------------------------------------------
__global__ __launch_bounds__(256) void ln_res_kernel(const float* __restrict__ A,
                                                     const ushort_t* __restrict__ Bv,
                                                     const float* __restrict__ g,
                                                     const float* __restrict__ be,
                                                     float* __restrict__ outf,
                                                     ushort_t* __restrict__ outb) {
  const int row = blockIdx.x;
  const int tid = threadIdx.x;
  const size_t base = (size_t)row * 1024;
  float4 a4 = ((const float4*)(A + base))[tid];
  us4 b4 = ((const us4*)(Bv + base))[tid];
  float v[4];
  v[0] = a4.x + b2f(b4.x);
  v[1] = a4.y + b2f(b4.y);
  v[2] = a4.z + b2f(b4.z);
  v[3] = a4.w + b2f(b4.w);
  float s = v[0] + v[1] + v[2] + v[3];
  float sq = v[0] * v[0] + v[1] * v[1] + v[2] * v[2] + v[3] * v[3];
#pragma unroll
  for (int off = 32; off; off >>= 1) {
    s += __shfl_xor(s, off);
    sq += __shfl_xor(sq, off);
  }
  __shared__ float ls[4], lsq[4];
  int wave = tid >> 6, lane = tid & 63;
  if (lane == 0) { ls[wave] = s; lsq[wave] = sq; }
  __syncthreads();
  s = ls[0] + ls[1] + ls[2] + ls[3];
  sq = lsq[0] + lsq[1] + lsq[2] + lsq[3];
  float mean = s * (1.f / 1024.f);
  float var = sq * (1.f / 1024.f) - mean * mean;
  float rstd = rsqrtf(var + 1e-5f);
  float4 g4 = ((const float4*)g)[tid];
  float4 e4 = ((const float4*)be)[tid];
  float o0 = (v[0] - mean) * rstd * g4.x + e4.x;
  float o1 = (v[1] - mean) * rstd * g4.y + e4.y;
  float o2 = (v[2] - mean) * rstd * g4.z + e4.z;
  float o3 = (v[3] - mean) * rstd * g4.w + e4.w;
  float4 of = {o0, o1, o2, o3};
  ((float4*)(outf + base))[tid] = of;
  if (outb) {
    us4 ob;
    ob.x = f2b(o0); ob.y = f2b(o1); ob.z = f2b(o2); ob.w = f2b(o3);
    ((us4*)(outb + base))[tid] = ob;
  }
}

// ---------------------------------------------------------------------------
// Workspace layout (bytes), lifetime-overlapped. Total <= 200 MiB.
// ---------------------------------------------------------------------------
#define O_XBF   ((size_t)0)            // x bf16 [8192][1024]     ; later x1 bf16
#define O_ROPED ((size_t)16777216)     // roped bf16 [8192][1024] ; later ctx bf16
#define O_W_IN  ((size_t)33554432)     // in_proj_w bf16 [3072][1024]
#define O_W_OUT ((size_t)39845888)     // out_proj_w bf16 [1024][1024]
#define O_W1    ((size_t)41943040)     // w1 bf16 [4096][1024]
#define O_W2    ((size_t)50331648)     // w2 bf16 [1024][4096]
#define O_BIG   ((size_t)58720256)     // qkv bf16 [8192][3072] ; then h bf16 ; then ff1 bf16
#define O_VT    ((size_t)125829120)    // V^T bf16 [B,H,HD,S]
#define O_X1F   ((size_t)142606336)    // x1 fp32 [8192][1024]
#define O_FF2   ((size_t)176160768)    // ff2 bf16 [8192][1024]

extern "C" void kernel_launch(void* const* d_in, const int* in_sizes, int n_in,
                              void* d_out, int out_size, void* d_ws, size_t ws_size,
                              hipStream_t stream) {
  const float* x          = (const float*)d_in[0];
  const float* in_proj_w  = (const float*)d_in[1];
  const float* in_proj_b  = (const float*)d_in[2];
  const float* out_proj_w = (const float*)d_in[3];
  const float* out_proj_b = (const float*)d_in[4];
  const float* ln1_g      = (const float*)d_in[5];
  const float* ln1_b      = (const float*)d_in[6];
  const float* w1         = (const float*)d_in[7];
  const float* b1         = (const float*)d_in[8];
  const float* w2         = (const float*)d_in[9];
  const float* b2         = (const float*)d_in[10];
  const float* ln2_g      = (const float*)d_in[11];
  const float* ln2_b      = (const float*)d_in[12];
  float* out = (float*)d_out;

  char* ws = (char*)d_ws;
  ushort_t* xbf     = (ushort_t*)(ws + O_XBF);
  ushort_t* roped   = (ushort_t*)(ws + O_ROPED);
  ushort_t* wbf_in  = (ushort_t*)(ws + O_W_IN);
  ushort_t* wbf_out = (ushort_t*)(ws + O_W_OUT);
  ushort_t* wbf_1   = (ushort_t*)(ws + O_W1);
  ushort_t* wbf_2   = (ushort_t*)(ws + O_W2);
  ushort_t* qkv_buf = (ushort_t*)(ws + O_BIG);
  ushort_t* vtb     = (ushort_t*)(ws + O_VT);
  ushort_t* ctx     = (ushort_t*)(ws + O_ROPED);  // reuse roped
  ushort_t* h_bf    = (ushort_t*)(ws + O_BIG);    // reuse qkv region
  float*    x1f     = (float*)(ws + O_X1F);
  ushort_t* x1bf    = (ushort_t*)(ws + O_XBF);    // reuse xbf
  ushort_t* ff1     = (ushort_t*)(ws + O_BIG);    // reuse h region (h dead)
  ushort_t* ff2     = (ushort_t*)(ws + O_FF2);

  dim3 blk(256);
  const int NOSPLIT = 1 << 30;

  // 1) weight casts to bf16 (single launch)
  cast4_kernel<<<dim3(12288), blk, 0, stream>>>(in_proj_w, out_proj_w, w1, w2,
                                                wbf_in, wbf_out, wbf_1, wbf_2);

  // 2) RoPE (+ x cast)
  rope_kernel<<<dim3(16384), blk, 0, stream>>>(x, roped, xbf);

  // 3) QKV merged: cols 0..2047 use roped, cols 2048.. use xbf (N=3072)
  gemm_bt<0><<<dim3(64 * 24), blk, 0, stream>>>(roped, xbf, 2048, wbf_in, in_proj_b,
                                                qkv_buf, QKV_, 1024);
  // 4) V transpose -> [B,H,HD,S]
  vtrans_kernel<<<dim3(2048), blk, 0, stream>>>(qkv_buf, vtb);

  // 5) windowed flash attention -> ctx bf16
  attn_kernel<<<dim3(2048), blk, 0, stream>>>(qkv_buf, vtb, ctx);

  // 6) h = ctx @ Wo^T + bo (bf16 out)
  gemm_bt<0><<<dim3(64 * 8), blk, 0, stream>>>(ctx, ctx, NOSPLIT, wbf_out, out_proj_b,
                                               h_bf, 1024, 1024);

  // 7) x1 = LN1(x + h) -> fp32 + bf16
  ln_res_kernel<<<dim3(8192), blk, 0, stream>>>(x, h_bf, ln1_g, ln1_b, x1f, x1bf);

  // 8) ff1 = gelu(x1 @ W1^T + b1) bf16  (N=4096)
  gemm_bt<1><<<dim3(64 * 32), blk, 0, stream>>>(x1bf, x1bf, NOSPLIT, wbf_1, b1,
                                                ff1, 4096, 1024);

  // 9) ff2 = ff1 @ W2^T + b2 (bf16, K=4096)
  gemm_bt<0><<<dim3(64 * 8), blk, 0, stream>>>(ff1, ff1, NOSPLIT, wbf_2, b2,
                                               ff2, 1024, 4096);

  // 10) out = LN2(x1 + ff2)
  ln_res_kernel<<<dim3(8192), blk, 0, stream>>>(x1f, ff2, ln2_g, ln2_b, out, nullptr);
}